// Round 16
// baseline (815.485 us; speedup 1.0000x reference)
//
#include <hip/hip_runtime.h>
#include <hip/hip_bf16.h>

// ---------- types ----------
typedef __attribute__((ext_vector_type(8))) short bfx8;    // 8 bf16 (4 VGPRs) MFMA A/B frag
typedef __attribute__((ext_vector_type(4))) short bfx4;    // 4 bf16 (2 VGPRs) for 32x32x8
typedef __attribute__((ext_vector_type(4))) float fx4;     // 16x16 C/D frag
typedef __attribute__((ext_vector_type(16))) float f32x16; // 32x32 C/D frag

#define MFMA16(a,b,c) __builtin_amdgcn_mfma_f32_16x16x32_bf16((a),(b),(c),0,0,0)
#define MFMA32(a,b,c) __builtin_amdgcn_mfma_f32_32x32x16_bf16((a),(b),(c),0,0,0)

// PV MFMA: 32x32 K=8, A/B = 4 bf16 (2 VGPRs). B[k][q]: k = 4*(lane>>5)+reg -> lane-local P quads.
__device__ __forceinline__ f32x16 mfma32x8(bfx4 a, bfx4 b, f32x16 c){
#if __has_builtin(__builtin_amdgcn_mfma_f32_32x32x8bf16_1k)
  return __builtin_amdgcn_mfma_f32_32x32x8bf16_1k(a, b, c, 0, 0, 0);
#else
  asm("v_mfma_f32_32x32x8_bf16 %0, %1, %2, %0" : "+v"(c) : "v"(a), "v"(b));
  return c;
#endif
}

// HW packed f32->bf16 (RNE). NOTE: inline asm is OPAQUE to the MFMA hazard
// recognizer -- its result must NOT feed an MFMA operand directly. Always keep a
// compiler-visible VALU op (the '& m' below) between cvtpk and the MFMA consumer
// (r13/r14 failed without it; r12/r15 passed with it).
__device__ __forceinline__ unsigned cvtpk(float lo, float hi){
  unsigned r;
  asm("v_cvt_pk_bf16_f32 %0, %1, %2" : "=v"(r) : "v"(lo), "v"(hi));
  return r;
}

__device__ __forceinline__ unsigned short bfc(float x){
  return __builtin_bit_cast(unsigned short, __float2bfloat16(x));
}
// 1-bit signed bitfield extract: 0 or 0xFFFFFFFF
__device__ __forceinline__ int sbfe1(unsigned v, int pos){
#if __has_builtin(__builtin_amdgcn_sbfe)
  return __builtin_amdgcn_sbfe((int)v, pos, 1);
#else
  return ((int)(v << (31-pos))) >> 31;
#endif
}
__device__ __forceinline__ bfx8 cvt8(const float* p){
  const float4* q = (const float4*)p;
  float4 a = q[0], b = q[1];
  bfx8 r;
  r[0]=(short)bfc(a.x); r[1]=(short)bfc(a.y); r[2]=(short)bfc(a.z); r[3]=(short)bfc(a.w);
  r[4]=(short)bfc(b.x); r[5]=(short)bfc(b.y); r[6]=(short)bfc(b.z); r[7]=(short)bfc(b.w);
  return r;
}
__device__ __forceinline__ void g2l16(const void* g, void* l){
  __builtin_amdgcn_global_load_lds((const __attribute__((address_space(1))) unsigned*)g,
                                   (__attribute__((address_space(3))) unsigned*)l, 16, 0, 0);
}
__device__ __forceinline__ f32x16 zero16(){
  f32x16 z;
  #pragma unroll
  for (int i=0;i<16;++i) z[i] = 0.f;
  return z;
}

#define SCL 0.04508422002778f   /* log2(e)/sqrt(1024) */

// ---------- kernel 1: projections + mask bitpack + Wo cast (merged) ----------
__global__ __launch_bounds__(256) void prep_k(const float* __restrict__ Xv, const float* __restrict__ Xk,
                                              const float* __restrict__ Xq,
                                              const float* __restrict__ Wv, const float* __restrict__ Wk,
                                              const float* __restrict__ Wq,
                                              const int* __restrict__ M, const float* __restrict__ Wo,
                                              unsigned short* __restrict__ Vt, unsigned short* __restrict__ Kb,
                                              unsigned short* __restrict__ Qb,
                                              unsigned long long* __restrict__ mT,
                                              unsigned short* __restrict__ Wob){
  int bid = blockIdx.x;
  int tid = threadIdx.x, l = tid & 63, wv = tid >> 6, g = l >> 4, j = l & 15;
  if (bid >= 3072){
    int pid = bid - 3072;
    if (pid < 1024){
      int task = pid*4 + wv;               // 4096 tasks: n(4) x kt(32) x qchunk(32)
      int n = task >> 10, rem = task & 1023, kt = rem >> 5, qc = rem & 31;
      int qbase = qc*64;
      const int* mp = M + (size_t)n*2048*2048 + (size_t)kt*64 + l;
      unsigned long long myw = 0;
      for (int qq = 0; qq < 64; ++qq){
        unsigned long long b = __ballot(mp[(size_t)(qbase+qq)*2048] != 0);
        if (l == qq) myw = b;
      }
      mT[((size_t)n*32 + kt)*2048 + qbase + l] = myw;
    } else {
      int i = ((pid-1024)*256 + tid)*8;    // 512 blocks cover 1024*1024
      bfx8 v = cvt8(Wo + i);
      *(bfx8*)(Wob + i) = v;
    }
    return;
  }
  int which = bid >> 10;                   // 0=v,1=k,2=q
  int r = bid & 1023;
  int nh = r >> 4, sb = r & 15;
  int n = nh >> 4, h = nh & 15;
  const float* X = (which==0) ? Xv : ((which==1) ? Xk : Xq);
  const float* W = (which==0) ? Wv : ((which==1) ? Wk : Wq);
  int s0 = sb*128 + wv*32;
  size_t xbase = (size_t)n*2048*1024 + (size_t)h*64;

  if (which){
    float sc = (which==2) ? SCL : 1.0f;
    bfx8 bw[4][2];
    for (int nt=0;nt<4;++nt) for (int ks=0;ks<2;++ks)
      bw[nt][ks] = cvt8(W + (nt*16 + j)*64 + ks*32 + g*8);
    bfx8 ax[2][2];
    for (int mt=0;mt<2;++mt){
      const float* xp = X + xbase + (size_t)(s0 + mt*16 + j)*1024;
      for (int ks=0;ks<2;++ks) ax[mt][ks] = cvt8(xp + ks*32 + g*8);
    }
    fx4 acc[2][4];
    for (int mt=0;mt<2;++mt) for (int nt=0;nt<4;++nt) acc[mt][nt] = (fx4){0.f,0.f,0.f,0.f};
    for (int mt=0;mt<2;++mt) for (int nt=0;nt<4;++nt) for (int ks=0;ks<2;++ks)
      acc[mt][nt] = MFMA16(ax[mt][ks], bw[nt][ks], acc[mt][nt]);
    unsigned short* O = ((which==1) ? Kb : Qb) + (size_t)nh*2048*64;
    for (int mt=0;mt<2;++mt) for (int nt=0;nt<4;++nt) for (int rr=0;rr<4;++rr){
      int s = s0 + mt*16 + g*4 + rr, e = nt*16 + j;
      O[(size_t)s*64 + e] = bfc(acc[mt][nt][rr]*sc);
    }
  } else {
    bfx8 aw[4][2];
    for (int mt=0;mt<4;++mt) for (int ks=0;ks<2;++ks)
      aw[mt][ks] = cvt8(W + (mt*16 + j)*64 + ks*32 + g*8);
    bfx8 bx[2][2];
    for (int nt=0;nt<2;++nt){
      const float* xp = X + xbase + (size_t)(s0 + nt*16 + j)*1024;
      for (int ks=0;ks<2;++ks) bx[nt][ks] = cvt8(xp + ks*32 + g*8);
    }
    fx4 acc[4][2];
    for (int mt=0;mt<4;++mt) for (int nt=0;nt<2;++nt) acc[mt][nt] = (fx4){0.f,0.f,0.f,0.f};
    for (int mt=0;mt<4;++mt) for (int nt=0;nt<2;++nt) for (int ks=0;ks<2;++ks)
      acc[mt][nt] = MFMA16(aw[mt][ks], bx[nt][ks], acc[mt][nt]);
    unsigned short* O = Vt + (size_t)nh*64*2048;
    for (int mt=0;mt<4;++mt) for (int nt=0;nt<2;++nt) for (int rr=0;rr<4;++rr){
      int d = mt*16 + g*4 + rr, s = s0 + nt*16 + j;
      O[(size_t)d*2048 + s] = bfc(acc[mt][nt][rr]);
    }
  }
}

// ---------- kernel 2: flash attention, 8-wave blocks, 32x32 QK + lane-local K=8 PV ----------
// grid: 512 (XCD-swizzled): 64 nh x 8 qblocks of 256 rows. 8 waves x 32 q-cols share
// one K/V staging: 512 lanes cover the 512 16B-chunks of K-tile + V-tile (1 g2l16 each),
// halving staging issue vs 4-wave; occupancy 4 blocks/CU = 32 waves/CU.
// Pack path = r15's verified form (exp2 -> sbfe1 float-mask -> cvtpk -> '& m' spacer).
__global__ __launch_bounds__(512, 8) void flash_k(const unsigned short* __restrict__ Qb,
                                                  const unsigned short* __restrict__ Kb,
                                                  const unsigned short* __restrict__ Vt,
                                                  const unsigned long long* __restrict__ mT,
                                                  unsigned short* __restrict__ AO){
  __shared__ short lK[2][64*64];   // [buf][kv row][128B]
  __shared__ short lV[2][64*64];   // [buf][d  row][128B]
  int tid = threadIdx.x;
  int l = tid & 63, wv = tid >> 6, hi = l >> 5, c = l & 31;
  int swc = (c & 7) ^ ((c >> 3) & 3);   // 16B-chunk swizzle for rows c / c+32
  int hi4 = hi*4;
  int bid0 = blockIdx.x;
  int bid = (bid0 & 7)*64 + (bid0 >> 3);    // XCD swizzle: each XCD gets 8 contiguous nh
  int nh = bid >> 3, qb = bid & 7;
  int n = nh >> 4, h = nh & 15;
  const unsigned short* Qp = Qb + (size_t)nh*131072;
  const unsigned short* Kp = Kb + (size_t)nh*131072;
  const unsigned short* Vp = Vt + (size_t)nh*131072;
  int q = qb*256 + wv*32 + c;
  bfx8 qf[4];
  #pragma unroll
  for (int s=0;s<4;++s) qf[s] = *(const bfx8*)(Qp + (size_t)q*64 + s*16 + hi*8);
  f32x16 accO0 = zero16(), accO1 = zero16();
  float ls = 0.f;
  const unsigned long long* mrow = mT + (size_t)n*65536 + q;
  int rowK0 = c*128;          // byte row offset (rows c)
  int rowK1 = rowK0 + 4096;   // rows c+32

  // staging: 512 lanes cover 512 chunks of each tile; 1 K + 1 V g2l16 per lane
  int sidx = tid;                            // 0..511
  int srow = sidx >> 3, scs = (sidx & 7) ^ (srow & 7) ^ ((srow >> 3) & 3);
  const unsigned short* Ksrc = Kp + (size_t)srow*64 + scs*8;
  const unsigned short* Vsrc = Vp + (size_t)srow*2048 + scs*8;

  #define STAGE(b, kt) do { \
    g2l16(Ksrc + (size_t)(kt)*4096, (char*)lK[b] + sidx*16); \
    g2l16(Vsrc + (size_t)(kt)*64,   (char*)lV[b] + sidx*16); \
  } while(0)

  STAGE(0, 0);
  __syncthreads();
  unsigned long long mwcur = mrow[0];

  // PROC_TILE: tile T covers kv 32T..32T+31. Word wi covers adjacent bits (pos,pos+1).
#define PROC_TILE(zz, mws, TT, VB) do { \
    unsigned Wt[8]; \
    _Pragma("unroll") \
    for (int wi=0; wi<8; ++wi){ \
      const int r0 = 2*wi; \
      const int pos = (r0&3) + 8*(r0>>2); \
      float p0_ = __builtin_amdgcn_exp2f((zz)[r0]); \
      float p1_ = __builtin_amdgcn_exp2f((zz)[r0+1]); \
      unsigned mlo = (unsigned)sbfe1((mws), pos); \
      unsigned mhi = (unsigned)sbfe1((mws), pos+1); \
      unsigned m = (mhi & 0xFFFF0000u) | (mlo & 0x0000FFFFu); \
      p0_ = __builtin_bit_cast(float, __builtin_bit_cast(unsigned,p0_) & mlo); \
      p1_ = __builtin_bit_cast(float, __builtin_bit_cast(unsigned,p1_) & mhi); \
      ls += p0_ + p1_; \
      Wt[wi] = cvtpk(p0_, p1_) & m; \
    } \
    _Pragma("unroll") \
    for (int wl=0; wl<4; ++wl){ \
      const int w = 4*(TT) + wl; \
      uint2 u2; u2.x = Wt[2*wl]; u2.y = Wt[2*wl+1]; \
      bfx4 pb = __builtin_bit_cast(bfx4, u2); \
      bfx4 vf0 = *(const bfx4*)((VB) + rowK0 + (((w ^ swc) << 4) + hi*8)); \
      bfx4 vf1 = *(const bfx4*)((VB) + rowK1 + (((w ^ swc) << 4) + hi*8)); \
      accO0 = mfma32x8(vf0, pb, accO0); \
      accO1 = mfma32x8(vf1, pb, accO1); \
    } \
  } while(0)

#define ATTN_ITER(BUF, NBUF, kt) do { \
    if ((kt) < 31) STAGE(NBUF, (kt)+1); \
    unsigned long long mw = mwcur; \
    mwcur = mrow[(size_t)((kt)+1 < 32 ? (kt)+1 : 31)*2048]; \
    const char* KB = (const char*)lK[BUF]; \
    const char* VB = (const char*)lV[BUF]; \
    f32x16 z0 = zero16(), z1 = zero16(); \
    _Pragma("unroll") \
    for (int s=0; s<4; ++s){ \
      bfx8 kf0 = *(const bfx8*)(KB + rowK0 + (((2*s+hi) ^ swc) << 4)); \
      bfx8 kf1 = *(const bfx8*)(KB + rowK1 + (((2*s+hi) ^ swc) << 4)); \
      z0 = MFMA32(kf0, qf[s], z0); \
      z1 = MFMA32(kf1, qf[s], z1); \
    } \
    unsigned mws0 = ((unsigned)mw) >> hi4; \
    unsigned mws1 = ((unsigned)(mw >> 32)) >> hi4; \
    PROC_TILE(z0, mws0, 0, VB); \
    PROC_TILE(z1, mws1, 1, VB); \
    __syncthreads(); \
  } while(0)

  #pragma unroll 1
  for (int kt2 = 0; kt2 < 32; kt2 += 2){
    ATTN_ITER(0, 1, kt2);
    ATTN_ITER(1, 0, kt2+1);
  }
#undef ATTN_ITER
#undef PROC_TILE
#undef STAGE

  ls += __shfl_xor(ls, 32);
  float inv = 1.0f / ls;
  unsigned short* aop = AO + ((size_t)n*2048 + q)*1024 + h*64;
  #pragma unroll
  for (int u=0; u<4; ++u){
    int d0 = u*8 + hi4;           // d-local = (r&3) + 8*(r>>2) + 4*hi, r=4u+rr
    uint2 o;
    o.x = cvtpk(accO0[4*u+0]*inv, accO0[4*u+1]*inv);
    o.y = cvtpk(accO0[4*u+2]*inv, accO0[4*u+3]*inv);
    *(uint2*)(aop + d0) = o;
    uint2 o1;
    o1.x = cvtpk(accO1[4*u+0]*inv, accO1[4*u+1]*inv);
    o1.y = cvtpk(accO1[4*u+2]*inv, accO1[4*u+3]*inv);
    *(uint2*)(aop + 32 + d0) = o1;
  }
}

// ---------- kernel 3: out = AO(8192x1024 bf16) @ Wo^T + bo (fp32), double-buffered ----------
__global__ __launch_bounds__(256) void gemm_k(const unsigned short* __restrict__ AO,
                                              const unsigned short* __restrict__ Wob,
                                              const float* __restrict__ bo, float* __restrict__ out){
  __shared__ short lA[2][128*32], lB[2][128*32];
  int tid = threadIdx.x, l = tid & 63, wv = tid >> 6, g = l >> 4, j = l & 15;
  int wr = wv >> 1, wc = wv & 1;
  int bid = blockIdx.x;
  int m0 = (bid >> 3)*128, n0 = (bid & 7)*128;
  fx4 acc[4][4];
  #pragma unroll
  for (int mt=0;mt<4;++mt) for (int nt=0;nt<4;++nt) acc[mt][nt] = (fx4){0.f,0.f,0.f,0.f};

  int sbase = wv*128;
  int sidx0 = sbase + l, sidx1 = sbase + 64 + l;
  int srow0 = sidx0 >> 2, sc0 = sidx0 & 3;
  int srow1 = sidx1 >> 2, sc1 = sidx1 & 3;
  const unsigned short* Asrc0 = AO  + (size_t)(m0+srow0)*1024 + sc0*8;
  const unsigned short* Asrc1 = AO  + (size_t)(m0+srow1)*1024 + sc1*8;
  const unsigned short* Bsrc0 = Wob + (size_t)(n0+srow0)*1024 + sc0*8;
  const unsigned short* Bsrc1 = Wob + (size_t)(n0+srow1)*1024 + sc1*8;

  #define GSTAGE(b, kb) do { \
    g2l16(Asrc0 + (kb)*32, (char*)lA[b] + sidx0*16); \
    g2l16(Asrc1 + (kb)*32, (char*)lA[b] + sidx1*16); \
    g2l16(Bsrc0 + (kb)*32, (char*)lB[b] + sidx0*16); \
    g2l16(Bsrc1 + (kb)*32, (char*)lB[b] + sidx1*16); \
  } while(0)

  GSTAGE(0, 0);
  __syncthreads();
  int b = 0;
  for (int kb = 0; kb < 32; ++kb){
    if (kb < 31) GSTAGE(b^1, kb+1);
    bfx8 af[4], bfr[4];
    #pragma unroll
    for (int mt=0;mt<4;++mt) af[mt]  = *(const bfx8*)((const char*)lA[b] + (wr*64 + mt*16 + j)*64 + g*16);
    #pragma unroll
    for (int nt=0;nt<4;++nt) bfr[nt] = *(const bfx8*)((const char*)lB[b] + (wc*64 + nt*16 + j)*64 + g*16);
    #pragma unroll
    for (int mt=0;mt<4;++mt)
      #pragma unroll
      for (int nt=0;nt<4;++nt)
        acc[mt][nt] = MFMA16(af[mt], bfr[nt], acc[mt][nt]);
    __syncthreads();
    b ^= 1;
  }
  #undef GSTAGE

  #pragma unroll
  for (int mt=0;mt<4;++mt)
    #pragma unroll
    for (int nt=0;nt<4;++nt){
      int mm = m0 + wr*64 + mt*16 + g*4;
      int oo = n0 + wc*64 + nt*16 + j;
      float bb = bo[oo];
      #pragma unroll
      for (int rr=0;rr<4;++rr)
        out[(size_t)(mm+rr)*1024 + oo] = acc[mt][nt][rr] + bb;
    }
}

// ---------- launch ----------
extern "C" void kernel_launch(void* const* d_in, const int* in_sizes, int n_in,
                              void* d_out, int out_size, void* d_ws, size_t ws_size,
                              hipStream_t stream){
  const float* V  = (const float*)d_in[0];
  const float* K  = (const float*)d_in[1];
  const float* Q  = (const float*)d_in[2];
  const int*   M  = (const int*)d_in[3];
  const float* Wv = (const float*)d_in[4];
  const float* Wk = (const float*)d_in[5];
  const float* Wq = (const float*)d_in[6];
  const float* Wo = (const float*)d_in[7];
  const float* bo = (const float*)d_in[8];

  char* ws = (char*)d_ws;
  unsigned short* Qb = (unsigned short*)(ws + ((size_t)0  << 20));  // 16MB
  unsigned short* Kb = (unsigned short*)(ws + ((size_t)16 << 20));  // 16MB
  unsigned short* Vt = (unsigned short*)(ws + ((size_t)32 << 20));  // 16MB
  unsigned short* AO = (unsigned short*)(ws + ((size_t)48 << 20));  // 16MB
  unsigned long long* mT = (unsigned long long*)(ws + ((size_t)64 << 20)); // 2MB
  unsigned short* Wob = (unsigned short*)(ws + ((size_t)66 << 20)); // 2MB

  hipLaunchKernelGGL(prep_k,  dim3(4608), dim3(256), 0, stream,
                     V, K, Q, Wv, Wk, Wq, M, Wo, Vt, Kb, Qb, mT, Wob);
  hipLaunchKernelGGL(flash_k, dim3(512),  dim3(512), 0, stream, Qb, Kb, Vt, mT, AO);
  hipLaunchKernelGGL(gemm_k,  dim3(512),  dim3(256), 0, stream, AO, Wob, bo, (float*)d_out);
}

// Round 17
// 186.968 us; speedup vs baseline: 4.3616x; 4.3616x over previous
//
#include <hip/hip_runtime.h>
#include <hip/hip_bf16.h>

// ---------- types ----------
typedef __attribute__((ext_vector_type(8))) short bfx8;    // 8 bf16 (4 VGPRs) MFMA A/B frag
typedef __attribute__((ext_vector_type(4))) short bfx4;    // 4 bf16 (2 VGPRs) for 32x32x8
typedef __attribute__((ext_vector_type(4))) float fx4;     // 16x16 C/D frag
typedef __attribute__((ext_vector_type(16))) float f32x16; // 32x32 C/D frag

#define MFMA16(a,b,c) __builtin_amdgcn_mfma_f32_16x16x32_bf16((a),(b),(c),0,0,0)
#define MFMA32(a,b,c) __builtin_amdgcn_mfma_f32_32x32x16_bf16((a),(b),(c),0,0,0)

// PV MFMA: 32x32 K=8, A/B = 4 bf16 (2 VGPRs). B[k][q]: k = 4*(lane>>5)+reg -> lane-local P quads.
__device__ __forceinline__ f32x16 mfma32x8(bfx4 a, bfx4 b, f32x16 c){
#if __has_builtin(__builtin_amdgcn_mfma_f32_32x32x8bf16_1k)
  return __builtin_amdgcn_mfma_f32_32x32x8bf16_1k(a, b, c, 0, 0, 0);
#else
  asm("v_mfma_f32_32x32x8_bf16 %0, %1, %2, %0" : "+v"(c) : "v"(a), "v"(b));
  return c;
#endif
}

// HW packed f32->bf16 (RNE). NOTE: inline asm is OPAQUE to the MFMA hazard
// recognizer -- its result must NOT feed an MFMA operand directly. Always keep a
// compiler-visible VALU op (the '& m' below) between cvtpk and the MFMA consumer
// (r13/r14 failed without it; r12/r15 passed with it).
__device__ __forceinline__ unsigned cvtpk(float lo, float hi){
  unsigned r;
  asm("v_cvt_pk_bf16_f32 %0, %1, %2" : "=v"(r) : "v"(lo), "v"(hi));
  return r;
}

__device__ __forceinline__ unsigned short bfc(float x){
  return __builtin_bit_cast(unsigned short, __float2bfloat16(x));
}
// 1-bit signed bitfield extract: 0 or 0xFFFFFFFF
__device__ __forceinline__ int sbfe1(unsigned v, int pos){
#if __has_builtin(__builtin_amdgcn_sbfe)
  return __builtin_amdgcn_sbfe((int)v, pos, 1);
#else
  return ((int)(v << (31-pos))) >> 31;
#endif
}
__device__ __forceinline__ bfx8 cvt8(const float* p){
  const float4* q = (const float4*)p;
  float4 a = q[0], b = q[1];
  bfx8 r;
  r[0]=(short)bfc(a.x); r[1]=(short)bfc(a.y); r[2]=(short)bfc(a.z); r[3]=(short)bfc(a.w);
  r[4]=(short)bfc(b.x); r[5]=(short)bfc(b.y); r[6]=(short)bfc(b.z); r[7]=(short)bfc(b.w);
  return r;
}
__device__ __forceinline__ void g2l16(const void* g, void* l){
  __builtin_amdgcn_global_load_lds((const __attribute__((address_space(1))) unsigned*)g,
                                   (__attribute__((address_space(3))) unsigned*)l, 16, 0, 0);
}
__device__ __forceinline__ f32x16 zero16(){
  f32x16 z;
  #pragma unroll
  for (int i=0;i<16;++i) z[i] = 0.f;
  return z;
}

#define SCL 0.04508422002778f   /* log2(e)/sqrt(1024) */

// ---------- kernel 1: projections + mask bitpack + Wo cast (merged) ----------
__global__ __launch_bounds__(256) void prep_k(const float* __restrict__ Xv, const float* __restrict__ Xk,
                                              const float* __restrict__ Xq,
                                              const float* __restrict__ Wv, const float* __restrict__ Wk,
                                              const float* __restrict__ Wq,
                                              const int* __restrict__ M, const float* __restrict__ Wo,
                                              unsigned short* __restrict__ Vt, unsigned short* __restrict__ Kb,
                                              unsigned short* __restrict__ Qb,
                                              unsigned long long* __restrict__ mT,
                                              unsigned short* __restrict__ Wob){
  int bid = blockIdx.x;
  int tid = threadIdx.x, l = tid & 63, wv = tid >> 6, g = l >> 4, j = l & 15;
  if (bid >= 3072){
    int pid = bid - 3072;
    if (pid < 1024){
      int task = pid*4 + wv;               // 4096 tasks: n(4) x kt(32) x qchunk(32)
      int n = task >> 10, rem = task & 1023, kt = rem >> 5, qc = rem & 31;
      int qbase = qc*64;
      const int* mp = M + (size_t)n*2048*2048 + (size_t)kt*64 + l;
      unsigned long long myw = 0;
      for (int qq = 0; qq < 64; ++qq){
        unsigned long long b = __ballot(mp[(size_t)(qbase+qq)*2048] != 0);
        if (l == qq) myw = b;
      }
      mT[((size_t)n*32 + kt)*2048 + qbase + l] = myw;
    } else {
      int i = ((pid-1024)*256 + tid)*8;    // 512 blocks cover 1024*1024
      bfx8 v = cvt8(Wo + i);
      *(bfx8*)(Wob + i) = v;
    }
    return;
  }
  int which = bid >> 10;                   // 0=v,1=k,2=q
  int r = bid & 1023;
  int nh = r >> 4, sb = r & 15;
  int n = nh >> 4, h = nh & 15;
  const float* X = (which==0) ? Xv : ((which==1) ? Xk : Xq);
  const float* W = (which==0) ? Wv : ((which==1) ? Wk : Wq);
  int s0 = sb*128 + wv*32;
  size_t xbase = (size_t)n*2048*1024 + (size_t)h*64;

  if (which){
    float sc = (which==2) ? SCL : 1.0f;
    bfx8 bw[4][2];
    for (int nt=0;nt<4;++nt) for (int ks=0;ks<2;++ks)
      bw[nt][ks] = cvt8(W + (nt*16 + j)*64 + ks*32 + g*8);
    bfx8 ax[2][2];
    for (int mt=0;mt<2;++mt){
      const float* xp = X + xbase + (size_t)(s0 + mt*16 + j)*1024;
      for (int ks=0;ks<2;++ks) ax[mt][ks] = cvt8(xp + ks*32 + g*8);
    }
    fx4 acc[2][4];
    for (int mt=0;mt<2;++mt) for (int nt=0;nt<4;++nt) acc[mt][nt] = (fx4){0.f,0.f,0.f,0.f};
    for (int mt=0;mt<2;++mt) for (int nt=0;nt<4;++nt) for (int ks=0;ks<2;++ks)
      acc[mt][nt] = MFMA16(ax[mt][ks], bw[nt][ks], acc[mt][nt]);
    unsigned short* O = ((which==1) ? Kb : Qb) + (size_t)nh*2048*64;
    for (int mt=0;mt<2;++mt) for (int nt=0;nt<4;++nt) for (int rr=0;rr<4;++rr){
      int s = s0 + mt*16 + g*4 + rr, e = nt*16 + j;
      O[(size_t)s*64 + e] = bfc(acc[mt][nt][rr]*sc);
    }
  } else {
    bfx8 aw[4][2];
    for (int mt=0;mt<4;++mt) for (int ks=0;ks<2;++ks)
      aw[mt][ks] = cvt8(W + (mt*16 + j)*64 + ks*32 + g*8);
    bfx8 bx[2][2];
    for (int nt=0;nt<2;++nt){
      const float* xp = X + xbase + (size_t)(s0 + nt*16 + j)*1024;
      for (int ks=0;ks<2;++ks) bx[nt][ks] = cvt8(xp + ks*32 + g*8);
    }
    fx4 acc[4][2];
    for (int mt=0;mt<4;++mt) for (int nt=0;nt<2;++nt) acc[mt][nt] = (fx4){0.f,0.f,0.f,0.f};
    for (int mt=0;mt<4;++mt) for (int nt=0;nt<2;++nt) for (int ks=0;ks<2;++ks)
      acc[mt][nt] = MFMA16(aw[mt][ks], bx[nt][ks], acc[mt][nt]);
    unsigned short* O = Vt + (size_t)nh*64*2048;
    for (int mt=0;mt<4;++mt) for (int nt=0;nt<2;++nt) for (int rr=0;rr<4;++rr){
      int d = mt*16 + g*4 + rr, s = s0 + nt*16 + j;
      O[(size_t)d*2048 + s] = bfc(acc[mt][nt][rr]);
    }
  }
}

// ---------- kernel 2: flash attention, 8-wave blocks, 32x32 QK + lane-local K=8 PV ----------
// grid: 512 (XCD-swizzled): 64 nh x 8 qblocks of 256 rows. 8 waves x 32 q-cols share
// one K/V staging (512 lanes = 512 chunks, 1 K + 1 V g2l16 per lane).
// launch_bounds(512,4): 128-VGPR ceiling -- r16's (512,8) capped at 64 and the compiler
// spilled everything to scratch (VGPR=32, 3.3GB scratch traffic). Per-thread state fits
// in ~64 (r15), so with slack the allocator lands ~64-80 -> 3-4 blocks/CU, no spill.
__global__ __launch_bounds__(512, 4) void flash_k(const unsigned short* __restrict__ Qb,
                                                  const unsigned short* __restrict__ Kb,
                                                  const unsigned short* __restrict__ Vt,
                                                  const unsigned long long* __restrict__ mT,
                                                  unsigned short* __restrict__ AO){
  __shared__ short lK[2][64*64];   // [buf][kv row][128B]
  __shared__ short lV[2][64*64];   // [buf][d  row][128B]
  int tid = threadIdx.x;
  int l = tid & 63, wv = tid >> 6, hi = l >> 5, c = l & 31;
  int swc = (c & 7) ^ ((c >> 3) & 3);   // 16B-chunk swizzle for rows c / c+32
  int hi4 = hi*4;
  int bid0 = blockIdx.x;
  int bid = (bid0 & 7)*64 + (bid0 >> 3);    // XCD swizzle: each XCD gets 8 contiguous nh
  int nh = bid >> 3, qb = bid & 7;
  int n = nh >> 4, h = nh & 15;
  const unsigned short* Qp = Qb + (size_t)nh*131072;
  const unsigned short* Kp = Kb + (size_t)nh*131072;
  const unsigned short* Vp = Vt + (size_t)nh*131072;
  int q = qb*256 + wv*32 + c;
  bfx8 qf[4];
  #pragma unroll
  for (int s=0;s<4;++s) qf[s] = *(const bfx8*)(Qp + (size_t)q*64 + s*16 + hi*8);
  f32x16 accO0 = zero16(), accO1 = zero16();
  float ls = 0.f;
  const unsigned long long* mrow = mT + (size_t)n*65536 + q;
  int rowK0 = c*128;          // byte row offset (rows c)
  int rowK1 = rowK0 + 4096;   // rows c+32

  // staging: 512 lanes cover 512 chunks of each tile; 1 K + 1 V g2l16 per lane
  int sidx = tid;                            // 0..511
  int srow = sidx >> 3, scs = (sidx & 7) ^ (srow & 7) ^ ((srow >> 3) & 3);
  const unsigned short* Ksrc = Kp + (size_t)srow*64 + scs*8;
  const unsigned short* Vsrc = Vp + (size_t)srow*2048 + scs*8;

  #define STAGE(b, kt) do { \
    g2l16(Ksrc + (size_t)(kt)*4096, (char*)lK[b] + sidx*16); \
    g2l16(Vsrc + (size_t)(kt)*64,   (char*)lV[b] + sidx*16); \
  } while(0)

  STAGE(0, 0);
  __syncthreads();
  unsigned long long mwcur = mrow[0];

  // PROC_TILE: tile T covers kv 32T..32T+31. Word wi covers adjacent bits (pos,pos+1).
#define PROC_TILE(zz, mws, TT, VB) do { \
    unsigned Wt[8]; \
    _Pragma("unroll") \
    for (int wi=0; wi<8; ++wi){ \
      const int r0 = 2*wi; \
      const int pos = (r0&3) + 8*(r0>>2); \
      float p0_ = __builtin_amdgcn_exp2f((zz)[r0]); \
      float p1_ = __builtin_amdgcn_exp2f((zz)[r0+1]); \
      unsigned mlo = (unsigned)sbfe1((mws), pos); \
      unsigned mhi = (unsigned)sbfe1((mws), pos+1); \
      unsigned m = (mhi & 0xFFFF0000u) | (mlo & 0x0000FFFFu); \
      p0_ = __builtin_bit_cast(float, __builtin_bit_cast(unsigned,p0_) & mlo); \
      p1_ = __builtin_bit_cast(float, __builtin_bit_cast(unsigned,p1_) & mhi); \
      ls += p0_ + p1_; \
      Wt[wi] = cvtpk(p0_, p1_) & m; \
    } \
    _Pragma("unroll") \
    for (int wl=0; wl<4; ++wl){ \
      const int w = 4*(TT) + wl; \
      uint2 u2; u2.x = Wt[2*wl]; u2.y = Wt[2*wl+1]; \
      bfx4 pb = __builtin_bit_cast(bfx4, u2); \
      bfx4 vf0 = *(const bfx4*)((VB) + rowK0 + (((w ^ swc) << 4) + hi*8)); \
      bfx4 vf1 = *(const bfx4*)((VB) + rowK1 + (((w ^ swc) << 4) + hi*8)); \
      accO0 = mfma32x8(vf0, pb, accO0); \
      accO1 = mfma32x8(vf1, pb, accO1); \
    } \
  } while(0)

#define ATTN_ITER(BUF, NBUF, kt) do { \
    if ((kt) < 31) STAGE(NBUF, (kt)+1); \
    unsigned long long mw = mwcur; \
    mwcur = mrow[(size_t)((kt)+1 < 32 ? (kt)+1 : 31)*2048]; \
    const char* KB = (const char*)lK[BUF]; \
    const char* VB = (const char*)lV[BUF]; \
    f32x16 z0 = zero16(), z1 = zero16(); \
    _Pragma("unroll") \
    for (int s=0; s<4; ++s){ \
      bfx8 kf0 = *(const bfx8*)(KB + rowK0 + (((2*s+hi) ^ swc) << 4)); \
      bfx8 kf1 = *(const bfx8*)(KB + rowK1 + (((2*s+hi) ^ swc) << 4)); \
      z0 = MFMA32(kf0, qf[s], z0); \
      z1 = MFMA32(kf1, qf[s], z1); \
    } \
    unsigned mws0 = ((unsigned)mw) >> hi4; \
    unsigned mws1 = ((unsigned)(mw >> 32)) >> hi4; \
    PROC_TILE(z0, mws0, 0, VB); \
    PROC_TILE(z1, mws1, 1, VB); \
    __syncthreads(); \
  } while(0)

  #pragma unroll 1
  for (int kt2 = 0; kt2 < 32; kt2 += 2){
    ATTN_ITER(0, 1, kt2);
    ATTN_ITER(1, 0, kt2+1);
  }
#undef ATTN_ITER
#undef PROC_TILE
#undef STAGE

  ls += __shfl_xor(ls, 32);
  float inv = 1.0f / ls;
  unsigned short* aop = AO + ((size_t)n*2048 + q)*1024 + h*64;
  #pragma unroll
  for (int u=0; u<4; ++u){
    int d0 = u*8 + hi4;           // d-local = (r&3) + 8*(r>>2) + 4*hi, r=4u+rr
    uint2 o;
    o.x = cvtpk(accO0[4*u+0]*inv, accO0[4*u+1]*inv);
    o.y = cvtpk(accO0[4*u+2]*inv, accO0[4*u+3]*inv);
    *(uint2*)(aop + d0) = o;
    uint2 o1;
    o1.x = cvtpk(accO1[4*u+0]*inv, accO1[4*u+1]*inv);
    o1.y = cvtpk(accO1[4*u+2]*inv, accO1[4*u+3]*inv);
    *(uint2*)(aop + 32 + d0) = o1;
  }
}

// ---------- kernel 3: out = AO(8192x1024 bf16) @ Wo^T + bo (fp32), double-buffered ----------
__global__ __launch_bounds__(256) void gemm_k(const unsigned short* __restrict__ AO,
                                              const unsigned short* __restrict__ Wob,
                                              const float* __restrict__ bo, float* __restrict__ out){
  __shared__ short lA[2][128*32], lB[2][128*32];
  int tid = threadIdx.x, l = tid & 63, wv = tid >> 6, g = l >> 4, j = l & 15;
  int wr = wv >> 1, wc = wv & 1;
  int bid = blockIdx.x;
  int m0 = (bid >> 3)*128, n0 = (bid & 7)*128;
  fx4 acc[4][4];
  #pragma unroll
  for (int mt=0;mt<4;++mt) for (int nt=0;nt<4;++nt) acc[mt][nt] = (fx4){0.f,0.f,0.f,0.f};

  int sbase = wv*128;
  int sidx0 = sbase + l, sidx1 = sbase + 64 + l;
  int srow0 = sidx0 >> 2, sc0 = sidx0 & 3;
  int srow1 = sidx1 >> 2, sc1 = sidx1 & 3;
  const unsigned short* Asrc0 = AO  + (size_t)(m0+srow0)*1024 + sc0*8;
  const unsigned short* Asrc1 = AO  + (size_t)(m0+srow1)*1024 + sc1*8;
  const unsigned short* Bsrc0 = Wob + (size_t)(n0+srow0)*1024 + sc0*8;
  const unsigned short* Bsrc1 = Wob + (size_t)(n0+srow1)*1024 + sc1*8;

  #define GSTAGE(b, kb) do { \
    g2l16(Asrc0 + (kb)*32, (char*)lA[b] + sidx0*16); \
    g2l16(Asrc1 + (kb)*32, (char*)lA[b] + sidx1*16); \
    g2l16(Bsrc0 + (kb)*32, (char*)lB[b] + sidx0*16); \
    g2l16(Bsrc1 + (kb)*32, (char*)lB[b] + sidx1*16); \
  } while(0)

  GSTAGE(0, 0);
  __syncthreads();
  int b = 0;
  for (int kb = 0; kb < 32; ++kb){
    if (kb < 31) GSTAGE(b^1, kb+1);
    bfx8 af[4], bfr[4];
    #pragma unroll
    for (int mt=0;mt<4;++mt) af[mt]  = *(const bfx8*)((const char*)lA[b] + (wr*64 + mt*16 + j)*64 + g*16);
    #pragma unroll
    for (int nt=0;nt<4;++nt) bfr[nt] = *(const bfx8*)((const char*)lB[b] + (wc*64 + nt*16 + j)*64 + g*16);
    #pragma unroll
    for (int mt=0;mt<4;++mt)
      #pragma unroll
      for (int nt=0;nt<4;++nt)
        acc[mt][nt] = MFMA16(af[mt], bfr[nt], acc[mt][nt]);
    __syncthreads();
    b ^= 1;
  }
  #undef GSTAGE

  #pragma unroll
  for (int mt=0;mt<4;++mt)
    #pragma unroll
    for (int nt=0;nt<4;++nt){
      int mm = m0 + wr*64 + mt*16 + g*4;
      int oo = n0 + wc*64 + nt*16 + j;
      float bb = bo[oo];
      #pragma unroll
      for (int rr=0;rr<4;++rr)
        out[(size_t)(mm+rr)*1024 + oo] = acc[mt][nt][rr] + bb;
    }
}

// ---------- launch ----------
extern "C" void kernel_launch(void* const* d_in, const int* in_sizes, int n_in,
                              void* d_out, int out_size, void* d_ws, size_t ws_size,
                              hipStream_t stream){
  const float* V  = (const float*)d_in[0];
  const float* K  = (const float*)d_in[1];
  const float* Q  = (const float*)d_in[2];
  const int*   M  = (const int*)d_in[3];
  const float* Wv = (const float*)d_in[4];
  const float* Wk = (const float*)d_in[5];
  const float* Wq = (const float*)d_in[6];
  const float* Wo = (const float*)d_in[7];
  const float* bo = (const float*)d_in[8];

  char* ws = (char*)d_ws;
  unsigned short* Qb = (unsigned short*)(ws + ((size_t)0  << 20));  // 16MB
  unsigned short* Kb = (unsigned short*)(ws + ((size_t)16 << 20));  // 16MB
  unsigned short* Vt = (unsigned short*)(ws + ((size_t)32 << 20));  // 16MB
  unsigned short* AO = (unsigned short*)(ws + ((size_t)48 << 20));  // 16MB
  unsigned long long* mT = (unsigned long long*)(ws + ((size_t)64 << 20)); // 2MB
  unsigned short* Wob = (unsigned short*)(ws + ((size_t)66 << 20)); // 2MB

  hipLaunchKernelGGL(prep_k,  dim3(4608), dim3(256), 0, stream,
                     V, K, Q, Wv, Wk, Wq, M, Wo, Vt, Kb, Qb, mT, Wob);
  hipLaunchKernelGGL(flash_k, dim3(512),  dim3(512), 0, stream, Qb, Kb, Vt, mT, AO);
  hipLaunchKernelGGL(gemm_k,  dim3(512),  dim3(256), 0, stream, AO, Wob, bo, (float*)d_out);
}